// Round 3
// baseline (207.565 us; speedup 1.0000x reference)
//
#include <hip/hip_runtime.h>
#include <hip/hip_bf16.h>

// DenseContrastiveLossV2 on MI355X — round 3.
// K0 k_gather : block (b,c) loads feat row coalesced to LDS, scatters samples
//               from LDS, writes FT[c][vec] bf16 (coalesced).   FT: 4 MB
// K1 k_norm   : transpose+L2-normalize -> F[vec][c] bf16; zeroes ns.
// K2 k_neg    : 64 rows x 128-col stages; A fragments pinned in VGPRs via asm,
//               B staged via global_load_lds (16B, XOR swizzle); per-row
//               sum exp(2*dot-2) over negative-label stages -> atomicAdd ns.
// K3 k_pos    : matching-label stages only; sum (d - log(exp d + ns[i])),
//               atomicAdd scalar loss.  (shift m=2 cancels exactly in logprob)

namespace {

constexpr int kC = 256;
constexpr int kHW = 96 * 96;   // 9216
constexpr int kT = 32;
constexpr int kV = 256;
constexpr int kM = kT * kV;    // 8192

typedef __attribute__((ext_vector_type(8))) short short8;  // 8 bf16
typedef __attribute__((ext_vector_type(4))) float f32x4;

__device__ inline unsigned short f2bf(float x) {
  __hip_bfloat16 h = __float2bfloat16(x);
  return __builtin_bit_cast(unsigned short, h);
}
__device__ inline float bf2f(unsigned short u) {
  unsigned int v = ((unsigned int)u) << 16;
  return __builtin_bit_cast(float, v);
}
__device__ inline void load_lds16(const unsigned short* g, unsigned short* l) {
  __builtin_amdgcn_global_load_lds(
      (const __attribute__((address_space(1))) void*)g,
      (__attribute__((address_space(3))) void*)l, 16, 0, 0);
}

}  // namespace

// ---------------- K0: gather (coalesced row staging) ----------------
__global__ __launch_bounds__(256) void k_gather(
    const float* __restrict__ feat, const int* __restrict__ binds,
    const int* __restrict__ sinds, unsigned short* __restrict__ FT) {
  const int b = (int)blockIdx.x;   // 0..7
  const int c = (int)blockIdx.y;   // 0..255
  __shared__ alignas(16) float row[kHW];
  __shared__ int s_b[kT];
  const int tid = (int)threadIdx.x;
  if (tid < kT) s_b[tid] = binds[tid];
  __syncthreads();
  bool any = false;
#pragma unroll
  for (int t = 0; t < kT; ++t) any |= (s_b[t] == b);
  if (!any) return;
  const float4* src4 = (const float4*)(feat + ((size_t)b * kC + c) * kHW);
  for (int i = tid; i < kHW / 4; i += 256) ((float4*)row)[i] = src4[i];
  __syncthreads();
  unsigned short* dst = FT + (size_t)c * kM;
  for (int t = 0; t < kT; ++t) {
    if (s_b[t] != b) continue;
    const int p = sinds[t * kV + tid];
    dst[t * kV + tid] = f2bf(row[p]);
  }
}

// ---------------- K1: transpose + normalize (+ zero ns) ----------------
__global__ __launch_bounds__(256) void k_norm(
    const unsigned short* __restrict__ FT, unsigned short* __restrict__ F,
    float* __restrict__ ns) {
  constexpr int PAD = 40;
  const int v0 = (int)blockIdx.x * 32;
  __shared__ alignas(16) unsigned short tile[kC][PAD];
  __shared__ float part[8][32];
  __shared__ float s_inv[32];
  const int tid = (int)threadIdx.x;
  if (tid < 32) ns[v0 + tid] = 0.f;
  {
    const int p4 = tid & 3, cb = tid >> 2;
    for (int c = cb; c < kC; c += 64) {
      int4 d = *(const int4*)(FT + (size_t)c * kM + v0 + p4 * 8);
      *(int4*)&tile[c][p4 * 8] = d;
    }
  }
  __syncthreads();
  {
    const int v = tid & 31, oct = tid >> 5;
    float ss = 0.f;
    for (int c = oct * 32; c < oct * 32 + 32; ++c) {
      float x = bf2f(tile[c][v]);
      ss += x * x;
    }
    part[oct][v] = ss;
  }
  __syncthreads();
  if (tid < 32) {
    float ss = 0.f;
#pragma unroll
    for (int o = 0; o < 8; ++o) ss += part[o][tid];
    s_inv[tid] = 1.0f / fmaxf(sqrtf(ss), 1e-12f);
  }
  __syncthreads();
#pragma unroll
  for (int p = 0; p < 4; ++p) {
    const int chunk = p * 256 + tid;
    const int v = chunk >> 5, c0 = (chunk & 31) << 3;
    const float inv = s_inv[v];
    alignas(16) unsigned short o[8];
#pragma unroll
    for (int k = 0; k < 8; ++k) o[k] = f2bf(bf2f(tile[c0 + k][v]) * inv);
    *(int4*)(F + (size_t)(v0 + v) * kC + c0) = *(const int4*)o;
  }
}

// ---------------- K2: negative sweep -> ns[row] ----------------
__global__ __launch_bounds__(256, 2) void k_neg(
    const unsigned short* __restrict__ F, const int* __restrict__ labels,
    float* __restrict__ ns) {
  const int tid = (int)threadIdx.x;
  const int w = tid >> 6, lane = tid & 63, q = lane >> 4, l16 = lane & 15;
  const int row0 = (int)blockIdx.y * 64;
  const int cx = (int)blockIdx.x;  // 0..3, 16 stages each
  __shared__ alignas(16) unsigned short Bt[128 * kC];  // 64 KB, swizzled
  __shared__ int s_lab[kT];
  __shared__ float s_red[4][64];
  if (tid < kT) s_lab[tid] = labels[tid];
  __syncthreads();
  const int labr = s_lab[row0 >> 8];

  // A fragments: 64 rows x K=256, pinned in 128 VGPRs.
  short8 af[4][8];
#pragma unroll
  for (int rg = 0; rg < 4; ++rg)
#pragma unroll
    for (int ks = 0; ks < 8; ++ks) {
      af[rg][ks] = *(const short8*)((const short*)F +
                                    (size_t)(row0 + rg * 16 + l16) * kC +
                                    ks * 32 + q * 8);
      asm volatile("" : "+v"(af[rg][ks]));  // pin: forbid remat in loop
    }

  int bofs[2][8];
#pragma unroll
  for (int cg2 = 0; cg2 < 2; ++cg2)
#pragma unroll
    for (int ks = 0; ks < 8; ++ks) {
      const int j2c = w * 16 + l16 + cg2 * 64;
      bofs[cg2][ks] = j2c * kC + (((ks * 4 + q) ^ (j2c & 31)) << 3);
    }

  float sacc[4][4] = {};
  for (int s = cx * 16; s < cx * 16 + 16; ++s) {  // stage = 128 cols
    if (s_lab[s >> 1] == labr) continue;          // stage is label-uniform
    __syncthreads();
    const unsigned short* src0 = F + ((size_t)s << 15);  // s*128*256
#pragma unroll
    for (int i = 0; i < 16; ++i) {
      const int n = w * 1024 + i * 64 + lane;
      const int j = n >> 5;
      const int m = (n & 31) ^ (j & 31);
      load_lds16(src0 + ((size_t)j << 8) + (m << 3),
                 Bt + ((size_t)(w * 1024 + i * 64) << 3));
    }
    __syncthreads();
#pragma unroll
    for (int cg2 = 0; cg2 < 2; ++cg2) {
      f32x4 acc[4];
#pragma unroll
      for (int rg = 0; rg < 4; ++rg) acc[rg] = (f32x4){0.f, 0.f, 0.f, 0.f};
#pragma unroll
      for (int ks = 0; ks < 8; ++ks) {
        short8 bf = *(const short8*)(Bt + bofs[cg2][ks]);
#pragma unroll
        for (int rg = 0; rg < 4; ++rg)
          acc[rg] = __builtin_amdgcn_mfma_f32_16x16x32_bf16(af[rg][ks], bf,
                                                            acc[rg], 0, 0, 0);
      }
#pragma unroll
      for (int rg = 0; rg < 4; ++rg)
#pragma unroll
        for (int r = 0; r < 4; ++r)
          sacc[rg][r] += __expf(fmaf(acc[rg][r], 2.f, -2.f));
    }
  }
#pragma unroll
  for (int rg = 0; rg < 4; ++rg)
#pragma unroll
    for (int r = 0; r < 4; ++r) {
      float v = sacc[rg][r];
      v += __shfl_xor(v, 1, 64);
      v += __shfl_xor(v, 2, 64);
      v += __shfl_xor(v, 4, 64);
      v += __shfl_xor(v, 8, 64);
      if (l16 == 0) s_red[w][rg * 16 + q * 4 + r] = v;
    }
  __syncthreads();
  if (tid < 64) {
    float v = s_red[0][tid] + s_red[1][tid] + s_red[2][tid] + s_red[3][tid];
    atomicAdd(&ns[row0 + tid], v);
  }
}

// ---------------- K3: positive sweep -> loss ----------------
__global__ __launch_bounds__(256, 2) void k_pos(
    const unsigned short* __restrict__ F, const int* __restrict__ labels,
    const float* __restrict__ ns, float* __restrict__ out) {
  const int tid = (int)threadIdx.x;
  const int w = tid >> 6, lane = tid & 63, q = lane >> 4, l16 = lane & 15;
  const int row0 = (int)blockIdx.y * 64;
  const int tcol = (int)blockIdx.x;  // 0..31
  __shared__ alignas(16) unsigned short Bt[128 * kC];
  __shared__ int s_lab[kT];
  __shared__ float s_pos[4];
  if (tid < kT) s_lab[tid] = labels[tid];
  __syncthreads();
  const int labr = s_lab[row0 >> 8];
  if (s_lab[tcol] != labr) return;  // block-uniform

  short8 af[4][8];
#pragma unroll
  for (int rg = 0; rg < 4; ++rg)
#pragma unroll
    for (int ks = 0; ks < 8; ++ks) {
      af[rg][ks] = *(const short8*)((const short*)F +
                                    (size_t)(row0 + rg * 16 + l16) * kC +
                                    ks * 32 + q * 8);
      asm volatile("" : "+v"(af[rg][ks]));
    }

  int bofs[2][8];
#pragma unroll
  for (int cg2 = 0; cg2 < 2; ++cg2)
#pragma unroll
    for (int ks = 0; ks < 8; ++ks) {
      const int j2c = w * 16 + l16 + cg2 * 64;
      bofs[cg2][ks] = j2c * kC + (((ks * 4 + q) ^ (j2c & 31)) << 3);
    }

  float nsv[4][4];
#pragma unroll
  for (int rg = 0; rg < 4; ++rg)
#pragma unroll
    for (int r = 0; r < 4; ++r)
      nsv[rg][r] = ns[row0 + rg * 16 + q * 4 + r];

  float pos = 0.f;
  for (int st = 0; st < 2; ++st) {
    const int s = tcol * 2 + st;
    __syncthreads();
    const unsigned short* src0 = F + ((size_t)s << 15);
#pragma unroll
    for (int i = 0; i < 16; ++i) {
      const int n = w * 1024 + i * 64 + lane;
      const int j = n >> 5;
      const int m = (n & 31) ^ (j & 31);
      load_lds16(src0 + ((size_t)j << 8) + (m << 3),
                 Bt + ((size_t)(w * 1024 + i * 64) << 3));
    }
    __syncthreads();
#pragma unroll
    for (int cg2 = 0; cg2 < 2; ++cg2) {
      f32x4 acc[4];
#pragma unroll
      for (int rg = 0; rg < 4; ++rg) acc[rg] = (f32x4){0.f, 0.f, 0.f, 0.f};
#pragma unroll
      for (int ks = 0; ks < 8; ++ks) {
        short8 bf = *(const short8*)(Bt + bofs[cg2][ks]);
#pragma unroll
        for (int rg = 0; rg < 4; ++rg)
          acc[rg] = __builtin_amdgcn_mfma_f32_16x16x32_bf16(af[rg][ks], bf,
                                                            acc[rg], 0, 0, 0);
      }
      const int jcol = s * 128 + w * 16 + l16 + cg2 * 64;
#pragma unroll
      for (int rg = 0; rg < 4; ++rg)
#pragma unroll
        for (int r = 0; r < 4; ++r) {
          const int i = row0 + rg * 16 + q * 4 + r;
          if (i != jcol) {
            float d = fmaf(acc[rg][r], 2.f, -2.f);
            pos += d - __logf(__expf(d) + nsv[rg][r]);
          }
        }
    }
  }
#pragma unroll
  for (int m = 1; m < 64; m <<= 1) pos += __shfl_xor(pos, m, 64);
  if (lane == 0) s_pos[w] = pos;
  __syncthreads();
  if (tid == 0) {
    float tot = s_pos[0] + s_pos[1] + s_pos[2] + s_pos[3];
    int matches = 0;
    for (int t = 0; t < kT; ++t) matches += (s_lab[t] == labr) ? 1 : 0;
    const float cnt = (float)(matches * kV - 1);
    atomicAdd(out, -tot / (cnt * (float)kM));
  }
}

extern "C" void kernel_launch(void* const* d_in, const int* in_sizes, int n_in,
                              void* d_out, int out_size, void* d_ws,
                              size_t ws_size, hipStream_t stream) {
  const float* feat = (const float*)d_in[0];
  const int* binds = (const int*)d_in[1];
  const int* sinds = (const int*)d_in[2];
  const int* labels = (const int*)d_in[3];
  float* out = (float*)d_out;
  unsigned short* FT = (unsigned short*)d_ws;            // 4 MB  [256][8192]
  unsigned short* F = FT + (size_t)kC * kM;              // 4 MB  [8192][256]
  float* ns = (float*)(F + (size_t)kM * kC);             // 32 KB [8192]

  hipMemsetAsync(d_out, 0, sizeof(float) * out_size, stream);
  k_gather<<<dim3(8, kC), 256, 0, stream>>>(feat, binds, sinds, FT);
  k_norm<<<kM / 32, 256, 0, stream>>>(FT, F, ns);
  k_neg<<<dim3(4, kM / 64), 256, 0, stream>>>(F, labels, ns);
  k_pos<<<dim3(kT, kM / 64), 256, 0, stream>>>(F, labels, ns, out);
}